// Round 7
// baseline (126.181 us; speedup 1.0000x reference)
//
#include <hip/hip_runtime.h>
#include <hip/hip_fp16.h>

typedef _Float16 f16;
typedef _Float16 f16x4 __attribute__((ext_vector_type(4)));
typedef _Float16 f16x8 __attribute__((ext_vector_type(8)));
typedef float f32x16 __attribute__((ext_vector_type(16)));

#define NSZ 256
#define NIMG 384

// 256-wide swizzled LDS index (halves)
__device__ __forceinline__ int sw(int r, int c) { return r * NSZ + (c ^ ((r & 15) << 3)); }
// 32-wide swizzled LDS index (halves) for the X staging chunk
__device__ __forceinline__ int swx(int r, int c) { return r * 32 + (c ^ ((r & 3) << 3)); }

// Fragment-layout offset: element (row r, col c) ->
// [tile=r>>5][chunk=c>>4][lane=((c>>3)&1)*32+(r&31)][j=c&7]
__device__ __forceinline__ int frag_off(int r, int c) {
  return (((((r >> 5) * 16 + (c >> 4)) << 6) + (((c >> 3) & 1) << 5) + (r & 31)) << 3) + (c & 7);
}

__device__ __forceinline__ unsigned pk2(float a, float b) {
  unsigned r;
  asm("v_cvt_pkrtz_f16_f32 %0, %1, %2" : "=v"(r) : "v"(a), "v"(b));
  return r;
}
// v_permlane32_swap_b32 a,b: a[32:63] <-> b[0:31]
__device__ __forceinline__ void swap32(unsigned& a, unsigned& b) {
  asm("v_permlane32_swap_b32 %0, %1" : "+v"(a), "+v"(b));
}

#define TBL_FRAG(Tf, tile, q, lane) (*(const f16x8*)&(Tf)[((((tile) * 16 + (q)) << 6) + (lane)) << 3])
#define MFMA32(a, b, c) __builtin_amdgcn_mfma_f32_32x32x16_f16((a), (b), (c), 0, 0, 0)

// Tables: Cf = frag(C[k][h]), CTf = frag(C^T[h][k]); g[b][i]; Kq[b] = roundup32(#rows g>=0.0099).
// g monotone-decreasing => rows n>=Kq have fade = g_k*g_n < 0.0099 < 0.01 for ALL k -> masked.
__global__ void prep_kernel(f16* __restrict__ Cf, f16* __restrict__ CTf,
                            float* __restrict__ g, int* __restrict__ Kq,
                            const float* __restrict__ t) {
  int k = blockIdx.x;
  int h = threadIdx.x;
  double scale = (k == 0) ? 0.0625 : 0.08838834764831844;  // sqrt(1/256), sqrt(2/256)
  double val = cos(3.14159265358979323846 * ((double)h + 0.5) * (double)k / 256.0) * scale;
  f16 vh = (f16)((float)val);
  Cf[frag_off(k, h)] = vh;
  CTf[frag_off(h, k)] = vh;
  int pred = 0;
  if (k < 128) {
    float tb = t[k];
    float sg = expf(-0.69314718055994531f * (1.0f - tb) + 2.99573227355399099f * tb);
    float tau = 0.5f * sg * sg;
    float f = 3.14159265358979f * (float)h / 256.0f;
    float gv = expf(-f * f * tau);
    g[k * NSZ + h] = gv;
    pred = (gv >= 0.0099f) ? 1 : 0;
  }
  int cnt = __syncthreads_count(pred);
  if (k < 128 && h == 0) {
    int K = ((cnt + 31) >> 5) << 5;
    if (K < 32) K = 32;
    if (K > 256) K = 256;
    Kq[k] = K;
  }
}

// kernelA: per (img, n-half): E'[k<Kq][n-band<Kq] = 0.999*mask(fade)*fade * (C X C^T)[k,n],
// stored dense in A-fragment layout via permlane packing.
__global__ __launch_bounds__(256, 2) void kernelA(
    const float* __restrict__ x, f16* __restrict__ Ep,
    const f16* __restrict__ Cf, const float* __restrict__ g,
    const int* __restrict__ KqA) {
  __shared__ f16 PT[128 * NSZ];  // 64KB: PT[n_loc 128][h 256] (sw)
  __shared__ f16 Xs[NSZ * 32];   // 16KB: X h-rows x 32-w chunk (swx)

  int bid = blockIdx.x;
  int wg = (bid & 7) * 96 + (bid >> 3);  // XCD-chunked bijective (768 = 8*96)
  int img = wg >> 1, half = wg & 1;
  int b = img / 3;
  int Kq = KqA[b];
  if (128 * half >= Kq) return;  // whole n-band masked: E' tiles here are zero & never read

  int t = threadIdx.x, lane = t & 63, wave = t >> 6;
  int l31 = lane & 31, hi = lane >> 5;
  int kh = hi * 8, hi4 = hi * 4;
  const float* X = x + (size_t)img * 65536;
  f16* Ef = Ep + (size_t)img * 65536;

  const f32x16 zz = {0.f, 0.f, 0.f, 0.f, 0.f, 0.f, 0.f, 0.f,
                     0.f, 0.f, 0.f, 0.f, 0.f, 0.f, 0.f, 0.f};
  f32x16 acc[2][4];
#pragma unroll
  for (int fi = 0; fi < 2; ++fi)
#pragma unroll
    for (int fj = 0; fj < 4; ++fj) acc[fi][fj] = zz;

  // ---- Phase 1: D1[h 256][n-band 128] = sum_w X[h,w] C[n,w], streaming 32-w chunks.
  int xr = t >> 3;        // + it*32 -> row
  int xc = (t & 7) * 4;   // 4 floats, coalesced 128B per 8 lanes
  float4 xa[8];
#pragma unroll
  for (int it = 0; it < 8; ++it)
    xa[it] = *(const float4*)&X[(it * 32 + xr) * NSZ + xc];

  for (int cw = 0; cw < 8; ++cw) {
#pragma unroll
    for (int it = 0; it < 8; ++it) {
      union { unsigned u[2]; f16x4 h; } v;
      v.u[0] = pk2(xa[it].x, xa[it].y);
      v.u[1] = pk2(xa[it].z, xa[it].w);
      *(f16x4*)&Xs[swx(it * 32 + xr, xc)] = v.h;
    }
    __syncthreads();  // Xs chunk ready
    if (cw < 7) {     // issue next chunk's loads AFTER barrier -> overlap with MFMA
#pragma unroll
      for (int it = 0; it < 8; ++it)
        xa[it] = *(const float4*)&X[(it * 32 + xr) * NSZ + (cw + 1) * 32 + xc];
    }
#pragma unroll
    for (int qp = 0; qp < 2; ++qp) {
      int qg = cw * 2 + qp;
      f16x8 a0 = *(const f16x8*)&Xs[swx(32 * (wave * 2 + 0) + l31, qp * 16 + kh)];
      f16x8 a1 = *(const f16x8*)&Xs[swx(32 * (wave * 2 + 1) + l31, qp * 16 + kh)];
#pragma unroll
      for (int fj = 0; fj < 4; ++fj) {
        if (128 * half + 32 * fj < Kq) {
          f16x8 bf = TBL_FRAG(Cf, 4 * half + fj, qg, lane);
          acc[0][fj] = MFMA32(a0, bf, acc[0][fj]);
          acc[1][fj] = MFMA32(a1, bf, acc[1][fj]);
        }
      }
    }
    __syncthreads();  // all waves done reading Xs before next overwrite
  }

  // writeT: PT[n_loc][h] = D1[h][n]  (rows h = v-pattern, cols n = lane)
#pragma unroll
  for (int fi = 0; fi < 2; ++fi) {
    int colbase = 32 * (wave * 2 + fi);  // h
#pragma unroll
    for (int fj = 0; fj < 4; ++fj) {
      if (128 * half + 32 * fj >= Kq) continue;
      int crow = 32 * fj + l31;  // n_loc
#pragma unroll
      for (int v2 = 0; v2 < 4; ++v2) {
        f16x4 hv;
        hv[0] = (f16)acc[fi][fj][v2 * 4 + 0];
        hv[1] = (f16)acc[fi][fj][v2 * 4 + 1];
        hv[2] = (f16)acc[fi][fj][v2 * 4 + 2];
        hv[3] = (f16)acc[fi][fj][v2 * 4 + 3];
        *(f16x4*)&PT[sw(crow, colbase + v2 * 8 + hi4)] = hv;
      }
    }
  }
  __syncthreads();

  // ---- Phase 2: E[k<Kq][n-tile = wave] = sum_h PT[n,h] C[k,h]  (D rows = n, cols = k)
  int nt_n = 128 * half + 32 * wave;  // wave's global n base
  if (nt_n >= Kq) return;
  int ktiles = Kq >> 5;

  f32x16 acc2[8];
#pragma unroll
  for (int kt = 0; kt < 8; ++kt) acc2[kt] = zz;

  for (int q = 0; q < 16; ++q) {  // reduction over h: full 256
    f16x8 a = *(const f16x8*)&PT[sw(32 * wave + l31, q * 16 + kh)];
#pragma unroll
    for (int kt = 0; kt < 8; ++kt) {
      if (kt < ktiles) {
        f16x8 bf = TBL_FRAG(Cf, kt, q, lane);
        acc2[kt] = MFMA32(a, bf, acc2[kt]);
      }
    }
  }

  // Epilogue: scale (exact mask), pack f16, permlane-assemble 16B frags, dense store.
  const float* gb = g + b * NSZ;
  float gn[16];
#pragma unroll
  for (int v2 = 0; v2 < 4; ++v2) {
    float4 g4 = *(const float4*)&gb[nt_n + v2 * 8 + hi4];
    gn[v2 * 4 + 0] = g4.x; gn[v2 * 4 + 1] = g4.y;
    gn[v2 * 4 + 2] = g4.z; gn[v2 * 4 + 3] = g4.w;
  }
#pragma unroll
  for (int kt = 0; kt < 8; ++kt) {
    if (kt >= ktiles) continue;
    float gk = gb[kt * 32 + l31];
    float sv[16];
#pragma unroll
    for (int e16 = 0; e16 < 16; ++e16) {
      float fade = gk * gn[e16];
      float s = (fade < 0.01f) ? 0.f : 0.999f * fade;
      sv[e16] = acc2[kt][e16] * s;
    }
    unsigned d[8];
#pragma unroll
    for (int v2 = 0; v2 < 4; ++v2) {
      d[v2 * 2 + 0] = pk2(sv[v2 * 4 + 0], sv[v2 * 4 + 1]);
      d[v2 * 2 + 1] = pk2(sv[v2 * 4 + 2], sv[v2 * 4 + 3]);
    }
#pragma unroll
    for (int vp = 0; vp < 2; ++vp) {
      unsigned A0 = d[vp * 4 + 0], B0 = d[vp * 4 + 2];
      unsigned A1 = d[vp * 4 + 1], B1 = d[vp * 4 + 3];
      swap32(A0, B0);  // A0 = dw0 (j0,1), B0 = dw2 (j4,5)
      swap32(A1, B1);  // A1 = dw1 (j2,3), B1 = dw3 (j6,7)
      int q = 8 * half + 2 * wave + vp;
      uint4 st = {A0, A1, B0, B1};
      *(uint4*)&Ef[(((kt * 16 + q) << 6) + lane) << 3] = st;  // 1KB dense per wave-instr
    }
  }
}

// kernelB: per (img, w-half): G[w][k<Kq] = (sum_{n<Kq} E'[k,n] C[n,w])^T;
// Y[h][w] = 0.001*X + sum_{k<Kq} C[k,h] G[w,k].
__global__ __launch_bounds__(256, 2) void kernelB(
    const float* __restrict__ x, const f16* __restrict__ Ep,
    float* __restrict__ out, const f16* __restrict__ CTf,
    const int* __restrict__ KqA) {
  __shared__ f16 G[128 * NSZ];  // 64KB [w_loc 128][k 256] (sw)

  int bid = blockIdx.x;
  int wg = (bid & 7) * 96 + (bid >> 3);
  int img = wg >> 1, half = wg & 1;
  int b = img / 3;
  int Kq = KqA[b], nq = Kq >> 4;

  int t = threadIdx.x, lane = t & 63, wave = t >> 6;
  int l31 = lane & 31, hi = lane >> 5, kh = hi * 8, hi4 = hi * 4;
  const f16* Ef = Ep + (size_t)img * 65536;
  const float* Xb = x + (size_t)img * 65536 + 128 * half;
  float* Y = out + (size_t)img * 65536 + 128 * half;

  const f32x16 zz = {0.f, 0.f, 0.f, 0.f, 0.f, 0.f, 0.f, 0.f,
                     0.f, 0.f, 0.f, 0.f, 0.f, 0.f, 0.f, 0.f};
  f32x16 acc[2][4];
#pragma unroll
  for (int fi = 0; fi < 2; ++fi)
#pragma unroll
    for (int fj = 0; fj < 4; ++fj) acc[fi][fj] = zz;

  // S3: D3[k (2 tiles/wave)][w-band 128] = sum_{n<Kq} E'[k,n] C[n,w]
  bool act0 = 32 * (2 * wave + 0) < Kq;
  bool act1 = 32 * (2 * wave + 1) < Kq;
  if (act0) {
#pragma unroll 2
    for (int q = 0; q < nq; ++q) {
      f16x8 a0 = TBL_FRAG(Ef, 2 * wave + 0, q, lane);
      f16x8 a1;
      if (act1) a1 = TBL_FRAG(Ef, 2 * wave + 1, q, lane);
#pragma unroll
      for (int fj = 0; fj < 4; ++fj) {
        f16x8 bf = TBL_FRAG(CTf, 4 * half + fj, q, lane);
        acc[0][fj] = MFMA32(a0, bf, acc[0][fj]);
        if (act1) acc[1][fj] = MFMA32(a1, bf, acc[1][fj]);
      }
    }
  }
  // writeT -> G[w][k] (only valid k tiles; G[:, k>=Kq] never read)
#pragma unroll
  for (int fi = 0; fi < 2; ++fi) {
    if (32 * (2 * wave + fi) >= Kq) continue;
    int colbase = 32 * (2 * wave + fi);  // k
#pragma unroll
    for (int fj = 0; fj < 4; ++fj) {
      int crow = 32 * fj + l31;  // w_loc
#pragma unroll
      for (int v2 = 0; v2 < 4; ++v2) {
        f16x4 hv;
        hv[0] = (f16)acc[fi][fj][v2 * 4 + 0];
        hv[1] = (f16)acc[fi][fj][v2 * 4 + 1];
        hv[2] = (f16)acc[fi][fj][v2 * 4 + 2];
        hv[3] = (f16)acc[fi][fj][v2 * 4 + 3];
        *(f16x4*)&G[sw(crow, colbase + v2 * 8 + hi4)] = hv;
      }
    }
  }
  __syncthreads();

  // S4: Y[h (2 tiles/wave)][w-band] = sum_{k<Kq} CT[h,k] G[w,k]
#pragma unroll
  for (int fi = 0; fi < 2; ++fi)
#pragma unroll
    for (int fj = 0; fj < 4; ++fj) acc[fi][fj] = zz;
#pragma unroll 2
  for (int q = 0; q < nq; ++q) {
    f16x8 a0 = TBL_FRAG(CTf, 2 * wave + 0, q, lane);
    f16x8 a1 = TBL_FRAG(CTf, 2 * wave + 1, q, lane);
    f16x8 bf[4];
#pragma unroll
    for (int fj = 0; fj < 4; ++fj)
      bf[fj] = *(const f16x8*)&G[sw(32 * fj + l31, q * 16 + kh)];
#pragma unroll
    for (int fj = 0; fj < 4; ++fj) {
      acc[0][fj] = MFMA32(a0, bf[fj], acc[0][fj]);
      acc[1][fj] = MFMA32(a1, bf[fj], acc[1][fj]);
    }
  }
  // store Y + exact 0.001*X identity term
#pragma unroll
  for (int fi = 0; fi < 2; ++fi)
#pragma unroll
    for (int fj = 0; fj < 4; ++fj) {
      int w = 32 * fj + l31;
#pragma unroll
      for (int v2 = 0; v2 < 4; ++v2)
#pragma unroll
        for (int e = 0; e < 4; ++e) {
          int h = 32 * (2 * wave + fi) + v2 * 8 + hi4 + e;
          Y[h * NSZ + w] = acc[fi][fj][v2 * 4 + e] + 0.001f * Xb[h * NSZ + w];
        }
    }
}

extern "C" void kernel_launch(void* const* d_in, const int* in_sizes, int n_in,
                              void* d_out, int out_size, void* d_ws, size_t ws_size,
                              hipStream_t stream) {
  const float* x = (const float*)d_in[0];
  const float* t = (const float*)d_in[1];
  float* out = (float*)d_out;

  char* ws = (char*)d_ws;
  float* g = (float*)ws;           // 131072 B
  f16* Cf = (f16*)(ws + 131072);   // 131072 B (frag layout)
  f16* CTf = (f16*)(ws + 262144);  // 131072 B (frag layout)
  int* Kq = (int*)(ws + 393216);   // 512 B
  f16* Ep = (f16*)(ws + 393728);   // 48 MB (A-frag layout, truncated region only)

  prep_kernel<<<256, 256, 0, stream>>>(Cf, CTf, g, Kq, t);
  kernelA<<<NIMG * 2, 256, 0, stream>>>(x, Ep, Cf, g, Kq);
  kernelB<<<NIMG * 2, 256, 0, stream>>>(x, Ep, out, CTf, Kq);
}